// Round 5
// baseline (823.472 us; speedup 1.0000x reference)
//
#include <hip/hip_runtime.h>
#include <math.h>

#define Cdim   256
#define Ssp    8192      // D*H*W
#define Npts   65536
#define NCODES 1024
#define BETA   0.25f
#define MT     64        // points per GEMM block
#define KTOT   768       // split-K: [zh | zh | zl] x [eh | el | eh]
#define NKC    48        // K-chunks of 16
#define ESCALE 8192.0f   // keep el out of f16-subnormal truncation
#define WS_NEED (65536 + (size_t)786432 * 2)

typedef _Float16 f16;
typedef f16   half8  __attribute__((ext_vector_type(8)));
typedef float f32x16 __attribute__((ext_vector_type(16)));

// ---------------- embed norms (fp32, same as passing rounds) ----------------
__global__ __launch_bounds__(256) void enorm_kernel(const float* __restrict__ embed,
                                                    float* __restrict__ enorm) {
    int j = blockIdx.x * 256 + threadIdx.x;
    if (j >= NCODES) return;
    const float4* row = reinterpret_cast<const float4*>(embed + (size_t)j * Cdim);
    float s = 0.f;
#pragma unroll 8
    for (int c4 = 0; c4 < Cdim / 4; ++c4) {
        float4 v = row[c4];
        s += v.x * v.x + v.y * v.y + v.z * v.z + v.w * v.w;
    }
    enorm[j] = s;
}

// ---------------- prep: split embed into f16 hi/lo, chunk-tiled ----------------
// Bws layout: [kc=48][code=1024][k'=16] f16 ; k = kc*16+k' ; rows: 0..255 eh,
// 256..511 el, 512..767 eh (paired against A=[zh zh zl]). Scaled by ESCALE.
__global__ __launch_bounds__(256) void prep_kernel(const float* __restrict__ embed,
                                                   f16* __restrict__ Bws) {
    int tid = blockIdx.x * 256 + threadIdx.x;   // 196608 threads, 4 elems each
    int o4 = tid * 4;
    int kc = o4 >> 14;
    int r  = o4 & 16383;
    int j  = r >> 4;
    int k0 = r & 15;
#pragma unroll
    for (int i = 0; i < 4; ++i) {
        int k = kc * 16 + k0 + i;
        int c = k & 255;
        float ev = embed[j * 256 + c] * ESCALE;
        f16 eh = (f16)ev;
        f16 v  = (k >= 256 && k < 512) ? (f16)(ev - (float)eh) : eh;
        Bws[o4 + i] = v;
    }
}

// ---------------- MFMA GEMM + fused argmin ----------------
// 256 thr (4 waves). Block: 64 points x all 1024 codes, K=768.
// Wave w owns codes [256w,256w+256): 2 m-frags x 8 n-frags of 32x32, acc=256 VGPR.
// A resident in LDS (96KB, XOR-swizzled 16B granules); B 16-k chunks, reg-prefetched.
__global__ __launch_bounds__(256, 1) void vq_gemm(const float* __restrict__ z,
                                                  const f16* __restrict__ Bws,
                                                  const float* __restrict__ enorm,
                                                  float* __restrict__ out_idx,
                                                  float* __restrict__ counts) {
    __shared__ __attribute__((aligned(16))) f16 As[MT * KTOT];      // 96 KB
    __shared__ __attribute__((aligned(16))) f16 Bt[NCODES * 24];    // 48 KB (16k + 8 pad)
    __shared__ float en_s[NCODES];                                  // 4 KB
    __shared__ float zn_s[MT];
    __shared__ float znp[4 * MT];
    __shared__ float redv[4 * MT];
    __shared__ int   redi[4 * MT];

    const int t  = threadIdx.x;
    const int l  = t & 63;
    const int w  = t >> 6;
    const int ln = l & 31;
    const int kb = l >> 5;            // which 8-k half of the 16-k step
    const int n0 = blockIdx.x * MT;
    const int b  = n0 >> 13;
    const int s0 = n0 & 8191;

    // ---- stage A: zh/zl from z (coalesced over p), + ||z||^2 partials ----
    {
        const int p  = t & 63;
        const int cq = t >> 6;
        const float* zb = z + (size_t)b * ((size_t)Cdim * Ssp) + s0;
        float zsq = 0.f;
        const int sw = (p & 7);
#pragma unroll 4
        for (int u = 0; u < 64; ++u) {
            int c = cq * 64 + u;
            float zv = zb[(size_t)c * Ssp + p];
            zsq += zv * zv;
            f16 zh = (f16)zv;
            f16 zl = (f16)(zv - (float)zh);
            int g0 = c >> 3;
            As[p * KTOT + 8 * (g0 ^ sw) + (c & 7)]        = zh;   // k = c
            As[p * KTOT + 8 * ((32 + g0) ^ sw) + (c & 7)] = zh;   // k = c+256
            As[p * KTOT + 8 * ((64 + g0) ^ sw) + (c & 7)] = zl;   // k = c+512
        }
        znp[cq * 64 + p] = zsq;
    }
    for (int i = t; i < NCODES; i += 256) en_s[i] = enorm[i];
    __syncthreads();
    if (t < MT) zn_s[t] = ((znp[t] + znp[64 + t]) + znp[128 + t]) + znp[192 + t];

    // ---- K loop: 48 chunks of 16 k; B reg-prefetch -> LDS -> 16 MFMA ----
    f32x16 acc[2][8] = {};
    half8 breg[8];
    {
        const f16* src = Bws;
#pragma unroll
        for (int i = 0; i < 8; ++i)
            breg[i] = *(const half8*)(src + (size_t)(i * 256 + t) * 8);
    }
#pragma unroll 1
    for (int kc = 0; kc < NKC; ++kc) {
        __syncthreads();                      // Bt readers done (covers A/zn on iter 0)
#pragma unroll
        for (int i = 0; i < 8; ++i) {
            int gi = i * 256 + t;             // granule id: 2 per code
            int j  = gi >> 1, g = gi & 1;
            *(half8*)&Bt[j * 24 + g * 8] = breg[i];
        }
        if (kc + 1 < NKC) {
            const f16* src = Bws + (size_t)(kc + 1) * 16384;
#pragma unroll
            for (int i = 0; i < 8; ++i)
                breg[i] = *(const half8*)(src + (size_t)(i * 256 + t) * 8);
        }
        __syncthreads();
        const int gs = ((kc * 2 + kb) ^ (l & 7));
        half8 a0 = *(const half8*)&As[(size_t)ln * KTOT + 8 * gs];
        half8 a1 = *(const half8*)&As[(size_t)(32 + ln) * KTOT + 8 * gs];
#pragma unroll
        for (int nn = 0; nn < 8; ++nn) {
            int j = w * 256 + nn * 32 + ln;
            half8 bf = *(const half8*)&Bt[j * 24 + kb * 8];
            acc[0][nn] = __builtin_amdgcn_mfma_f32_32x32x16_f16(a0, bf, acc[0][nn], 0, 0, 0);
            acc[1][nn] = __builtin_amdgcn_mfma_f32_32x32x16_f16(a1, bf, acc[1][nn], 0, 0, 0);
        }
    }

    // ---- scores + argmin. C layout (32x32): col=lane&31, row=(reg&3)+8*(reg>>2)+4*(lane>>5)
    const int h = l >> 5;
#pragma unroll
    for (int mm = 0; mm < 2; ++mm) {
#pragma unroll
        for (int rg = 0; rg < 16; ++rg) {
            const int row = mm * 32 + (rg & 3) + 8 * (rg >> 2) + 4 * h;
            const float znv = zn_s[row];
            float bv = 3.0e38f; int bi = 0;
#pragma unroll
            for (int nn = 0; nn < 8; ++nn) {
                int col = w * 256 + nn * 32 + ln;
                // ref rounding: fl( fl(zn+en) - fl(2*dot) ); dot = acc/ESCALE exact
                float k1 = znv + en_s[col];
                float sc = k1 - acc[mm][nn][rg] * (2.0f / ESCALE);
                if (sc < bv) { bv = sc; bi = col; }
            }
#pragma unroll
            for (int off = 1; off < 32; off <<= 1) {
                float ov = __shfl_xor(bv, off, 64);
                int   oi = __shfl_xor(bi, off, 64);
                if (ov < bv || (ov == bv && oi < bi)) { bv = ov; bi = oi; }
            }
            if (ln == 0) { redv[w * 64 + row] = bv; redi[w * 64 + row] = bi; }
        }
    }
    __syncthreads();
    if (t < MT) {
        float bv = redv[t]; int bi = redi[t];
#pragma unroll
        for (int ww = 1; ww < 4; ++ww) {
            float ov = redv[ww * 64 + t]; int oi = redi[ww * 64 + t];
            if (ov < bv || (ov == bv && oi < bi)) { bv = ov; bi = oi; }
        }
        out_idx[n0 + t] = (float)bi;
        atomicAdd(&counts[bi], 1.0f);
    }
}

// ---------------- epilogue: z_q gather-write + commitment loss ----------------
__global__ __launch_bounds__(256) void vq_epi(const float* __restrict__ z,
                                              const float* __restrict__ embed,
                                              const float* __restrict__ out_idx,
                                              float* __restrict__ out_zq,
                                              float* __restrict__ loss_acc) {
    const int n = blockIdx.x * 256 + threadIdx.x;
    const int b = n >> 13, s = n & 8191;
    const int idx = (int)out_idx[n];
    const float4* er = reinterpret_cast<const float4*>(embed + (size_t)idx * Cdim);
    const float* zp = z + (size_t)b * ((size_t)Cdim * Ssp) + s;
    float* oq = out_zq + (size_t)b * ((size_t)Cdim * Ssp) + s;
    float lsum = 0.f;
#pragma unroll 4
    for (int c4 = 0; c4 < Cdim / 4; ++c4) {
        float4 e = er[c4];
        const int c = c4 * 4;
        float z0 = zp[(size_t)(c + 0) * Ssp], z1 = zp[(size_t)(c + 1) * Ssp];
        float z2 = zp[(size_t)(c + 2) * Ssp], z3 = zp[(size_t)(c + 3) * Ssp];
        oq[(size_t)(c + 0) * Ssp] = e.x;
        oq[(size_t)(c + 1) * Ssp] = e.y;
        oq[(size_t)(c + 2) * Ssp] = e.z;
        oq[(size_t)(c + 3) * Ssp] = e.w;
        float d0 = z0 - e.x, d1 = z1 - e.y, d2 = z2 - e.z, d3 = z3 - e.w;
        lsum += d0 * d0 + d1 * d1 + d2 * d2 + d3 * d3;
    }
#pragma unroll
    for (int off = 32; off > 0; off >>= 1) lsum += __shfl_down(lsum, off, 64);
    if ((threadIdx.x & 63) == 0) atomicAdd(loss_acc, lsum);
}

// ================= fallback (round-4 verified kernel, used if ws too small) =================
#define PTS 64
#define CT  128
#define KC  32
__global__ __launch_bounds__(256, 2) void vq_main_fb(const float* __restrict__ z,
                                                     const float* __restrict__ embed,
                                                     const float* __restrict__ enorm,
                                                     float* __restrict__ out_zq,
                                                     float* __restrict__ out_idx,
                                                     float* __restrict__ loss_acc,
                                                     float* __restrict__ counts) {
    __shared__ __attribute__((aligned(16))) float smem[Cdim * PTS + KC * CT];
    float* zt = smem;
    float* et = smem + Cdim * PTS;
    const int t  = threadIdx.x;
    const int n0 = blockIdx.x * PTS;
    const int b  = n0 >> 13;
    const int s0 = n0 & 8191;
    const float* zb = z + (size_t)b * Cdim * Ssp + s0;
    {
        const int p4 = (t & 15) * 4, crow = t >> 4;
#pragma unroll
        for (int it = 0; it < 16; ++it) {
            int c = it * 16 + crow;
            float4 v = *reinterpret_cast<const float4*>(zb + (size_t)c * Ssp + p4);
            *reinterpret_cast<float4*>(&zt[c * PTS + p4]) = v;
        }
    }
    __syncthreads();
    {
        const int p = t & 63, qq = t >> 6;
        float sacc = 0.f;
#pragma unroll 8
        for (int c = qq * 64; c < qq * 64 + 64; ++c) { float v = zt[c * PTS + p]; sacc += v * v; }
        et[qq * 64 + p] = sacc;
    }
    __syncthreads();
    const int pg = t & 15, jg = t >> 4;
    const int p0 = pg * 4;
    float zn[4];
#pragma unroll
    for (int i = 0; i < 4; ++i) {
        int p = p0 + i;
        zn[i] = ((et[p] + et[64 + p]) + et[128 + p]) + et[192 + p];
    }
    float bestv[4] = {3.0e38f, 3.0e38f, 3.0e38f, 3.0e38f};
    int   besti[4] = {0, 0, 0, 0};
    const int dj = t >> 3, q = t & 7;
    const int sw_st = (q & 3) << 3;
    for (int jt = 0; jt < NCODES / CT; ++jt) {
        const int J0 = jt * CT;
        float acc[4][8];
#pragma unroll
        for (int i = 0; i < 4; ++i)
#pragma unroll
            for (int m = 0; m < 8; ++m) acc[i][m] = 0.f;
        for (int ks = 0; ks < Cdim / KC; ++ks) {
            const int cc0 = ks * KC;
            __syncthreads();
#pragma unroll
            for (int i = 0; i < 4; ++i) {
                const int jrel = dj + 32 * i;
                const float4 v = *reinterpret_cast<const float4*>(
                    embed + (size_t)(J0 + jrel) * Cdim + cc0 + q * 4);
                const int c0 = q * 4;
                const int jsw = jrel ^ sw_st;
                et[(c0 + 0) * CT + jsw] = v.x;
                et[(c0 + 1) * CT + jsw] = v.y;
                et[(c0 + 2) * CT + jsw] = v.z;
                et[(c0 + 3) * CT + jsw] = v.w;
            }
            __syncthreads();
#pragma unroll 4
            for (int c = 0; c < KC; ++c) {
                const float4 zp = *reinterpret_cast<const float4*>(&zt[(cc0 + c) * PTS + p0]);
                const int jb = (jg * 8) ^ (((c >> 2) & 3) << 3);
                const float4 ea = *reinterpret_cast<const float4*>(&et[c * CT + jb]);
                const float4 eb = *reinterpret_cast<const float4*>(&et[c * CT + jb + 4]);
                const float zc[4] = {zp.x, zp.y, zp.z, zp.w};
                const float ec[8] = {ea.x, ea.y, ea.z, ea.w, eb.x, eb.y, eb.z, eb.w};
#pragma unroll
                for (int i = 0; i < 4; ++i)
#pragma unroll
                    for (int m = 0; m < 8; ++m) acc[i][m] += zc[i] * ec[m];
            }
        }
#pragma unroll
        for (int m = 0; m < 8; ++m) {
            const int cid = J0 + jg * 8 + m;
            const float en = enorm[cid];
#pragma unroll
            for (int i = 0; i < 4; ++i) {
                float k1 = zn[i] + en;
                float sc = k1 - 2.0f * acc[i][m];
                if (sc < bestv[i]) { bestv[i] = sc; besti[i] = cid; }
            }
        }
    }
    __syncthreads();
    float* rv = et; int* ri = (int*)(et + 1024); int* idxf = (int*)(et + 2048);
#pragma unroll
    for (int i = 0; i < 4; ++i) { int p = p0 + i; rv[p * 16 + jg] = bestv[i]; ri[p * 16 + jg] = besti[i]; }
    __syncthreads();
    if (t < PTS) {
        int p = t;
        float bv = rv[p * 16]; int bi = ri[p * 16];
        for (int g = 1; g < 16; ++g) {
            float v = rv[p * 16 + g]; int ii = ri[p * 16 + g];
            if (v < bv || (v == bv && ii < bi)) { bv = v; bi = ii; }
        }
        idxf[p] = bi;
        out_idx[n0 + p] = (float)bi;
        atomicAdd(&counts[bi], 1.0f);
    }
    __syncthreads();
    float lsum = 0.f;
    {
        const int p = t & 63, cbase = t >> 6;
        const int myidx = idxf[p];
        const float4* erow4 = reinterpret_cast<const float4*>(embed + (size_t)myidx * Cdim);
        float* ob = out_zq + (size_t)b * Cdim * Ssp + s0 + p;
#pragma unroll 4
        for (int pass = 0; pass < 16; ++pass) {
            int c = cbase * 64 + pass * 4;
            float4 e = erow4[c >> 2];
            ob[(size_t)(c + 0) * Ssp] = e.x;
            ob[(size_t)(c + 1) * Ssp] = e.y;
            ob[(size_t)(c + 2) * Ssp] = e.z;
            ob[(size_t)(c + 3) * Ssp] = e.w;
            float d0 = zt[(c + 0) * PTS + p] - e.x;
            float d1 = zt[(c + 1) * PTS + p] - e.y;
            float d2 = zt[(c + 2) * PTS + p] - e.z;
            float d3 = zt[(c + 3) * PTS + p] - e.w;
            lsum += d0 * d0 + d1 * d1 + d2 * d2 + d3 * d3;
        }
    }
#pragma unroll
    for (int off = 32; off > 0; off >>= 1) lsum += __shfl_down(lsum, off, 64);
    if ((t & 63) == 0) atomicAdd(loss_acc, lsum);
}

// ---------------- finalize ----------------
__global__ __launch_bounds__(1024) void vq_final(const float* __restrict__ counts,
                                                 const float* __restrict__ loss_acc,
                                                 float* __restrict__ out_loss,
                                                 float* __restrict__ out_perp) {
    __shared__ float red[16];
    int t = threadIdx.x;
    float cnt = counts[t];
    float avg = cnt * (1.0f / (float)Npts);
    float term = avg * logf(avg + 1e-10f);
#pragma unroll
    for (int off = 32; off > 0; off >>= 1) term += __shfl_down(term, off, 64);
    if ((t & 63) == 0) red[t >> 6] = term;
    __syncthreads();
    if (t == 0) {
        float s = 0.f;
        for (int i = 0; i < 16; ++i) s += red[i];
        *out_perp = expf(-s);
        *out_loss = BETA * loss_acc[0] * (1.0f / 16777216.0f);
    }
}

extern "C" void kernel_launch(void* const* d_in, const int* in_sizes, int n_in,
                              void* d_out, int out_size, void* d_ws, size_t ws_size,
                              hipStream_t stream) {
    const float* z     = (const float*)d_in[0];
    const float* embed = (const float*)d_in[1];

    float* ws       = (float*)d_ws;
    float* loss_acc = ws;            // [0]
    float* counts   = ws + 64;       // [1024]
    float* enorm    = ws + 2048;     // [1024]

    float* out_zq   = (float*)d_out;
    float* out_idx  = out_zq + (size_t)Npts * Cdim;
    float* out_loss = out_idx + Npts;
    float* out_perp = out_loss + 1;

    hipMemsetAsync(d_ws, 0, 2048 * sizeof(float), stream);
    enorm_kernel<<<NCODES / 256, 256, 0, stream>>>(embed, enorm);

    if (ws_size >= WS_NEED) {
        f16* Bws = (f16*)((char*)d_ws + 65536);
        prep_kernel<<<768, 256, 0, stream>>>(embed, Bws);
        vq_gemm<<<Npts / MT, 256, 0, stream>>>(z, Bws, enorm, out_idx, counts);
        vq_epi<<<Npts / 256, 256, 0, stream>>>(z, embed, out_idx, out_zq, loss_acc);
    } else {
        vq_main_fb<<<Npts / PTS, 256, 0, stream>>>(z, embed, enorm, out_zq, out_idx,
                                                   loss_acc, counts);
    }
    vq_final<<<1, 1024, 0, stream>>>(counts, loss_acc, out_loss, out_perp);
}

// Round 6
// 224.418 us; speedup vs baseline: 3.6694x; 3.6694x over previous
//
#include <hip/hip_runtime.h>
#include <math.h>

#define Cdim   256
#define Ssp    8192      // D*H*W
#define Npts   65536
#define NCODES 1024
#define BETA   0.25f
#define MT     64        // points per GEMM block
#define NKC    48        // K-chunks of 16 (K=768 split: [zh|zh|zl] x [eh|el|eh])
#define ESCALE 8192.0f   // keep el out of f16-subnormal truncation
#define WS_NEED (65536 + (size_t)786432 * 2)

typedef _Float16 f16;
typedef f16   half8  __attribute__((ext_vector_type(8)));
typedef float f32x16 __attribute__((ext_vector_type(16)));

#define MFMA16(A, B, C) __builtin_amdgcn_mfma_f32_32x32x16_f16(A, B, C, 0, 0, 0)

// ---------------- embed norms ----------------
__global__ __launch_bounds__(256) void enorm_kernel(const float* __restrict__ embed,
                                                    float* __restrict__ enorm) {
    int j = blockIdx.x * 256 + threadIdx.x;
    if (j >= NCODES) return;
    const float4* row = reinterpret_cast<const float4*>(embed + (size_t)j * Cdim);
    float s = 0.f;
#pragma unroll 8
    for (int c4 = 0; c4 < Cdim / 4; ++c4) {
        float4 v = row[c4];
        s += v.x * v.x + v.y * v.y + v.z * v.z + v.w * v.w;
    }
    enorm[j] = s;
}

// ---------------- prep: split embed into f16 hi/lo, chunk-tiled ----------------
// Bws: [kc=48][code=1024][k'=16] f16. k = kc*16+k'; k 0..255 -> eh, 256..511 -> el,
// 512..767 -> eh. Scaled by ESCALE. (verified in round 5)
__global__ __launch_bounds__(256) void prep_kernel(const float* __restrict__ embed,
                                                   f16* __restrict__ Bws) {
    int tid = blockIdx.x * 256 + threadIdx.x;
    int o4 = tid * 4;
    int kc = o4 >> 14;
    int r  = o4 & 16383;
    int j  = r >> 4;
    int k0 = r & 15;
#pragma unroll
    for (int i = 0; i < 4; ++i) {
        int k = kc * 16 + k0 + i;
        int c = k & 255;
        float ev = embed[j * 256 + c] * ESCALE;
        f16 eh = (f16)ev;
        f16 v  = (k >= 256 && k < 512) ? (f16)(ev - (float)eh) : eh;
        Bws[o4 + i] = v;
    }
}

// ---------------- MFMA GEMM + fused argmin (v2) ----------------
// 256 thr / 4 waves, 64 points x 1024 codes, K=768 processed as 2 code-halves.
// A = [zh|zl] compact 64KB LDS (XOR-swizzled granules), read-only after 1 barrier.
// B fragments loaded DIRECT global->reg (16B/lane contiguous, L2-resident 1.5MB),
// register-prefetched one chunk ahead. No barriers in the K-loop. acc=128 VGPR.
__global__ __launch_bounds__(256, 2) void vq_gemm(const float* __restrict__ z,
                                                  const f16* __restrict__ Bws,
                                                  const float* __restrict__ enorm,
                                                  float* __restrict__ out_idx,
                                                  float* __restrict__ counts) {
    __shared__ __attribute__((aligned(16))) f16 As[MT * 512];   // 64 KB
    __shared__ float en_s[NCODES];                              // 4 KB
    __shared__ float znp[256];
    __shared__ float zn_s[MT];
    __shared__ float redv[8 * MT];                              // (jh,w) x row
    __shared__ int   redi[8 * MT];

    const int t  = threadIdx.x;
    const int l  = t & 63;
    const int w  = t >> 6;
    const int ln = l & 31;
    const int kb = l >> 5;
    const int n0 = blockIdx.x * MT;
    const int b  = n0 >> 13;
    const int s0 = n0 & 8191;

    // ---- stage A (zh granules 0..31, zl granules 32..63, swizzle g^=(p&7)) ----
    {
        const int p = t & 63;
        const int q = t >> 6;                 // c-quad, 64 c each
        const float* zb = z + (size_t)b * ((size_t)Cdim * Ssp) + s0;
        float zsq = 0.f;
#pragma unroll
        for (int gi = 0; gi < 8; ++gi) {
            const int c0 = q * 64 + gi * 8;
            half8 hh, ll;
#pragma unroll
            for (int u = 0; u < 8; ++u) {     // c ascending -> zsq order == round 2/5
                float zv = zb[(size_t)(c0 + u) * Ssp + p];
                zsq += zv * zv;
                f16 zh = (f16)zv;
                hh[u] = zh;
                ll[u] = (f16)(zv - (float)zh);
            }
            const int g0 = c0 >> 3;           // 0..31
            *(half8*)&As[p * 512 + 8 * (g0 ^ (p & 7))]        = hh;
            *(half8*)&As[p * 512 + 8 * ((32 + g0) ^ (p & 7))] = ll;
        }
        znp[q * 64 + p] = zsq;
    }
    for (int i = t; i < NCODES; i += 256) en_s[i] = enorm[i];
    __syncthreads();
    if (t < MT) zn_s[t] = ((znp[t] + znp[64 + t]) + znp[128 + t]) + znp[192 + t];
    __syncthreads();

    // ---- two code-halves of 512; wave w owns 128 codes per half ----
#pragma unroll 1
    for (int jh = 0; jh < 2; ++jh) {
        f32x16 acc[2][4] = {};
        const f16* bbase = Bws + (size_t)(jh * 512 + w * 128 + ln) * 16 + kb * 8;

        half8 b0 = *(const half8*)(bbase);
        half8 b1 = *(const half8*)(bbase + 512);
        half8 b2 = *(const half8*)(bbase + 1024);
        half8 b3 = *(const half8*)(bbase + 1536);

#pragma unroll 2
        for (int kc = 0; kc < NKC; ++kc) {
            const int gg = (kc < 16) ? (2 * kc + kb)
                         : (kc < 32) ? (2 * (kc - 16) + kb)
                                     : (32 + 2 * (kc - 32) + kb);
            const int gsw = 8 * (gg ^ (ln & 7));
            half8 a0 = *(const half8*)&As[ln * 512 + gsw];
            half8 a1 = *(const half8*)&As[(32 + ln) * 512 + gsw];

            half8 n0r = b0, n1 = b1, n2 = b2, n3 = b3;
            if (kc + 1 < NKC) {
                const f16* src = bbase + (size_t)(kc + 1) * 16384;
                n0r = *(const half8*)(src);
                n1  = *(const half8*)(src + 512);
                n2  = *(const half8*)(src + 1024);
                n3  = *(const half8*)(src + 1536);
            }
            acc[0][0] = MFMA16(a0, b0, acc[0][0]);
            acc[1][0] = MFMA16(a1, b0, acc[1][0]);
            acc[0][1] = MFMA16(a0, b1, acc[0][1]);
            acc[1][1] = MFMA16(a1, b1, acc[1][1]);
            acc[0][2] = MFMA16(a0, b2, acc[0][2]);
            acc[1][2] = MFMA16(a1, b2, acc[1][2]);
            acc[0][3] = MFMA16(a0, b3, acc[0][3]);
            acc[1][3] = MFMA16(a1, b3, acc[1][3]);
            b0 = n0r; b1 = n1; b2 = n2; b3 = n3;
        }

        // ---- scores + per-half argmin. C layout: col=lane&31,
        //      row=(reg&3)+8*(reg>>2)+4*(lane>>5)  (verified round 5) ----
        const int h = l >> 5;
#pragma unroll
        for (int mm = 0; mm < 2; ++mm) {
#pragma unroll
            for (int rg = 0; rg < 16; ++rg) {
                const int row = mm * 32 + (rg & 3) + 8 * (rg >> 2) + 4 * h;
                const float znv = zn_s[row];
                float bv = 3.0e38f; int bi = 0;
#pragma unroll
                for (int nn = 0; nn < 4; ++nn) {
                    const int col = jh * 512 + w * 128 + nn * 32 + ln;
                    float k1 = znv + en_s[col];
                    float sc = k1 - acc[mm][nn][rg] * (2.0f / ESCALE);
                    if (sc < bv) { bv = sc; bi = col; }
                }
#pragma unroll
                for (int off = 1; off < 32; off <<= 1) {
                    float ov = __shfl_xor(bv, off, 64);
                    int   oi = __shfl_xor(bi, off, 64);
                    if (ov < bv || (ov == bv && oi < bi)) { bv = ov; bi = oi; }
                }
                if (ln == 0) {
                    redv[(jh * 4 + w) * MT + row] = bv;
                    redi[(jh * 4 + w) * MT + row] = bi;
                }
            }
        }
    }
    __syncthreads();
    if (t < MT) {
        float bv = redv[t]; int bi = redi[t];
#pragma unroll
        for (int s = 1; s < 8; ++s) {
            float ov = redv[s * MT + t]; int oi = redi[s * MT + t];
            if (ov < bv || (ov == bv && oi < bi)) { bv = ov; bi = oi; }
        }
        out_idx[n0 + t] = (float)bi;
        atomicAdd(&counts[bi], 1.0f);
    }
}

// ---------------- epilogue: z_q gather-write + commitment loss ----------------
__global__ __launch_bounds__(256) void vq_epi(const float* __restrict__ z,
                                              const float* __restrict__ embed,
                                              const float* __restrict__ out_idx,
                                              float* __restrict__ out_zq,
                                              float* __restrict__ loss_acc) {
    const int n = blockIdx.x * 256 + threadIdx.x;
    const int b = n >> 13, s = n & 8191;
    const int idx = (int)out_idx[n];
    const float4* er = reinterpret_cast<const float4*>(embed + (size_t)idx * Cdim);
    const float* zp = z + (size_t)b * ((size_t)Cdim * Ssp) + s;
    float* oq = out_zq + (size_t)b * ((size_t)Cdim * Ssp) + s;
    float lsum = 0.f;
#pragma unroll 4
    for (int c4 = 0; c4 < Cdim / 4; ++c4) {
        float4 e = er[c4];
        const int c = c4 * 4;
        float z0 = zp[(size_t)(c + 0) * Ssp], z1 = zp[(size_t)(c + 1) * Ssp];
        float z2 = zp[(size_t)(c + 2) * Ssp], z3 = zp[(size_t)(c + 3) * Ssp];
        oq[(size_t)(c + 0) * Ssp] = e.x;
        oq[(size_t)(c + 1) * Ssp] = e.y;
        oq[(size_t)(c + 2) * Ssp] = e.z;
        oq[(size_t)(c + 3) * Ssp] = e.w;
        float d0 = z0 - e.x, d1 = z1 - e.y, d2 = z2 - e.z, d3 = z3 - e.w;
        lsum += d0 * d0 + d1 * d1 + d2 * d2 + d3 * d3;
    }
#pragma unroll
    for (int off = 32; off > 0; off >>= 1) lsum += __shfl_down(lsum, off, 64);
    if ((threadIdx.x & 63) == 0) atomicAdd(loss_acc, lsum);
}

// ================= fallback (round-4 verified kernel, used if ws too small) =================
#define PTS 64
#define CT  128
#define KC  32
__global__ __launch_bounds__(256, 2) void vq_main_fb(const float* __restrict__ z,
                                                     const float* __restrict__ embed,
                                                     const float* __restrict__ enorm,
                                                     float* __restrict__ out_zq,
                                                     float* __restrict__ out_idx,
                                                     float* __restrict__ loss_acc,
                                                     float* __restrict__ counts) {
    __shared__ __attribute__((aligned(16))) float smem[Cdim * PTS + KC * CT];
    float* zt = smem;
    float* et = smem + Cdim * PTS;
    const int t  = threadIdx.x;
    const int n0 = blockIdx.x * PTS;
    const int b  = n0 >> 13;
    const int s0 = n0 & 8191;
    const float* zb = z + (size_t)b * Cdim * Ssp + s0;
    {
        const int p4 = (t & 15) * 4, crow = t >> 4;
#pragma unroll
        for (int it = 0; it < 16; ++it) {
            int c = it * 16 + crow;
            float4 v = *reinterpret_cast<const float4*>(zb + (size_t)c * Ssp + p4);
            *reinterpret_cast<float4*>(&zt[c * PTS + p4]) = v;
        }
    }
    __syncthreads();
    {
        const int p = t & 63, qq = t >> 6;
        float sacc = 0.f;
#pragma unroll 8
        for (int c = qq * 64; c < qq * 64 + 64; ++c) { float v = zt[c * PTS + p]; sacc += v * v; }
        et[qq * 64 + p] = sacc;
    }
    __syncthreads();
    const int pg = t & 15, jg = t >> 4;
    const int p0 = pg * 4;
    float zn[4];
#pragma unroll
    for (int i = 0; i < 4; ++i) {
        int p = p0 + i;
        zn[i] = ((et[p] + et[64 + p]) + et[128 + p]) + et[192 + p];
    }
    float bestv[4] = {3.0e38f, 3.0e38f, 3.0e38f, 3.0e38f};
    int   besti[4] = {0, 0, 0, 0};
    const int dj = t >> 3, q = t & 7;
    const int sw_st = (q & 3) << 3;
    for (int jt = 0; jt < NCODES / CT; ++jt) {
        const int J0 = jt * CT;
        float acc[4][8];
#pragma unroll
        for (int i = 0; i < 4; ++i)
#pragma unroll
            for (int m = 0; m < 8; ++m) acc[i][m] = 0.f;
        for (int ks = 0; ks < Cdim / KC; ++ks) {
            const int cc0 = ks * KC;
            __syncthreads();
#pragma unroll
            for (int i = 0; i < 4; ++i) {
                const int jrel = dj + 32 * i;
                const float4 v = *reinterpret_cast<const float4*>(
                    embed + (size_t)(J0 + jrel) * Cdim + cc0 + q * 4);
                const int c0 = q * 4;
                const int jsw = jrel ^ sw_st;
                et[(c0 + 0) * CT + jsw] = v.x;
                et[(c0 + 1) * CT + jsw] = v.y;
                et[(c0 + 2) * CT + jsw] = v.z;
                et[(c0 + 3) * CT + jsw] = v.w;
            }
            __syncthreads();
#pragma unroll 4
            for (int c = 0; c < KC; ++c) {
                const float4 zp = *reinterpret_cast<const float4*>(&zt[(cc0 + c) * PTS + p0]);
                const int jb = (jg * 8) ^ (((c >> 2) & 3) << 3);
                const float4 ea = *reinterpret_cast<const float4*>(&et[c * CT + jb]);
                const float4 eb = *reinterpret_cast<const float4*>(&et[c * CT + jb + 4]);
                const float zc[4] = {zp.x, zp.y, zp.z, zp.w};
                const float ec[8] = {ea.x, ea.y, ea.z, ea.w, eb.x, eb.y, eb.z, eb.w};
#pragma unroll
                for (int i = 0; i < 4; ++i)
#pragma unroll
                    for (int m = 0; m < 8; ++m) acc[i][m] += zc[i] * ec[m];
            }
        }
#pragma unroll
        for (int m = 0; m < 8; ++m) {
            const int cid = J0 + jg * 8 + m;
            const float en = enorm[cid];
#pragma unroll
            for (int i = 0; i < 4; ++i) {
                float k1 = zn[i] + en;
                float sc = k1 - 2.0f * acc[i][m];
                if (sc < bestv[i]) { bestv[i] = sc; besti[i] = cid; }
            }
        }
    }
    __syncthreads();
    float* rv = et; int* ri = (int*)(et + 1024); int* idxf = (int*)(et + 2048);
#pragma unroll
    for (int i = 0; i < 4; ++i) { int p = p0 + i; rv[p * 16 + jg] = bestv[i]; ri[p * 16 + jg] = besti[i]; }
    __syncthreads();
    if (t < PTS) {
        int p = t;
        float bv = rv[p * 16]; int bi = ri[p * 16];
        for (int g = 1; g < 16; ++g) {
            float v = rv[p * 16 + g]; int ii = ri[p * 16 + g];
            if (v < bv || (v == bv && ii < bi)) { bv = v; bi = ii; }
        }
        idxf[p] = bi;
        out_idx[n0 + p] = (float)bi;
        atomicAdd(&counts[bi], 1.0f);
    }
    __syncthreads();
    float lsum = 0.f;
    {
        const int p = t & 63, cbase = t >> 6;
        const int myidx = idxf[p];
        const float4* erow4 = reinterpret_cast<const float4*>(embed + (size_t)myidx * Cdim);
        float* ob = out_zq + (size_t)b * Cdim * Ssp + s0 + p;
#pragma unroll 4
        for (int pass = 0; pass < 16; ++pass) {
            int c = cbase * 64 + pass * 4;
            float4 e = erow4[c >> 2];
            ob[(size_t)(c + 0) * Ssp] = e.x;
            ob[(size_t)(c + 1) * Ssp] = e.y;
            ob[(size_t)(c + 2) * Ssp] = e.z;
            ob[(size_t)(c + 3) * Ssp] = e.w;
            float d0 = zt[(c + 0) * PTS + p] - e.x;
            float d1 = zt[(c + 1) * PTS + p] - e.y;
            float d2 = zt[(c + 2) * PTS + p] - e.z;
            float d3 = zt[(c + 3) * PTS + p] - e.w;
            lsum += d0 * d0 + d1 * d1 + d2 * d2 + d3 * d3;
        }
    }
#pragma unroll
    for (int off = 32; off > 0; off >>= 1) lsum += __shfl_down(lsum, off, 64);
    if ((t & 63) == 0) atomicAdd(loss_acc, lsum);
}

// ---------------- finalize ----------------
__global__ __launch_bounds__(1024) void vq_final(const float* __restrict__ counts,
                                                 const float* __restrict__ loss_acc,
                                                 float* __restrict__ out_loss,
                                                 float* __restrict__ out_perp) {
    __shared__ float red[16];
    int t = threadIdx.x;
    float cnt = counts[t];
    float avg = cnt * (1.0f / (float)Npts);
    float term = avg * logf(avg + 1e-10f);
#pragma unroll
    for (int off = 32; off > 0; off >>= 1) term += __shfl_down(term, off, 64);
    if ((t & 63) == 0) red[t >> 6] = term;
    __syncthreads();
    if (t == 0) {
        float s = 0.f;
        for (int i = 0; i < 16; ++i) s += red[i];
        *out_perp = expf(-s);
        *out_loss = BETA * loss_acc[0] * (1.0f / 16777216.0f);
    }
}

extern "C" void kernel_launch(void* const* d_in, const int* in_sizes, int n_in,
                              void* d_out, int out_size, void* d_ws, size_t ws_size,
                              hipStream_t stream) {
    const float* z     = (const float*)d_in[0];
    const float* embed = (const float*)d_in[1];

    float* ws       = (float*)d_ws;
    float* loss_acc = ws;            // [0]
    float* counts   = ws + 64;       // [1024]
    float* enorm    = ws + 2048;     // [1024]

    float* out_zq   = (float*)d_out;
    float* out_idx  = out_zq + (size_t)Npts * Cdim;
    float* out_loss = out_idx + Npts;
    float* out_perp = out_loss + 1;

    hipMemsetAsync(d_ws, 0, 2048 * sizeof(float), stream);
    enorm_kernel<<<NCODES / 256, 256, 0, stream>>>(embed, enorm);

    if (ws_size >= WS_NEED) {
        f16* Bws = (f16*)((char*)d_ws + 65536);
        prep_kernel<<<768, 256, 0, stream>>>(embed, Bws);
        vq_gemm<<<Npts / MT, 256, 0, stream>>>(z, Bws, enorm, out_idx, counts);
        vq_epi<<<Npts / 256, 256, 0, stream>>>(z, embed, out_idx, out_zq, loss_acc);
    } else {
        vq_main_fb<<<Npts / PTS, 256, 0, stream>>>(z, embed, enorm, out_zq, out_idx,
                                                   loss_acc, counts);
    }
    vq_final<<<1, 1024, 0, stream>>>(counts, loss_acc, out_loss, out_perp);
}